// Round 1
// 447.199 us; speedup vs baseline: 1.0024x; 1.0024x over previous
//
#include <hip/hip_runtime.h>
#include <math.h>

// Problem constants
#define Vv 32000
#define Ee 1024
#define Hh 1024
#define Aa 10
#define Ss 512
#define Bb 64
#define Mm (Ss * Bb)   // 32768 rows of enc viewed as (s*64+b)

typedef __attribute__((ext_vector_type(8))) short bf16x8;   // 8 bf16 = 4 VGPRs
typedef __attribute__((ext_vector_type(4))) short s16x4;
typedef __attribute__((ext_vector_type(4))) float f32x4;

// fp32 -> bf16 (round-to-nearest-even), bit trick
__device__ inline short f2bf(float f) {
    union { float f; unsigned int u; } v;
    v.f = f;
    unsigned int r = (v.u + 0x7FFFu + ((v.u >> 16) & 1u)) >> 16;
    return (short)r;
}

__device__ inline bf16x8 cvt8(float4 lo, float4 hi) {
    bf16x8 r;
    r[0] = f2bf(lo.x); r[1] = f2bf(lo.y); r[2] = f2bf(lo.z); r[3] = f2bf(lo.w);
    r[4] = f2bf(hi.x); r[5] = f2bf(hi.y); r[6] = f2bf(hi.z); r[7] = f2bf(hi.w);
    return r;
}

// ---------------------------------------------------------------------------
// hpart[b][a] = sum_k Wa1[a][k] * h_last[b][k]  (k in [0,1024): "hh" half)
// fp32 exact. 4 waves k-split + shfl reduce; ONE barrier (was 90).
// grid(64), block(256)
__global__ __launch_bounds__(256) void hpart_kernel(const float* __restrict__ Wa1,
                                                    const float* __restrict__ h,
                                                    float* __restrict__ hpart) {
    __shared__ float part[4][16];
    const int b = blockIdx.x, t = threadIdx.x;
    const int w = t >> 6, lane = t & 63;
    const float* hb_ = h + (size_t)b * Hh;
    float p[Aa];
#pragma unroll
    for (int a = 0; a < Aa; a++) p[a] = 0.f;
#pragma unroll
    for (int i = 0; i < 4; i++) {
        const int k = w * 256 + i * 64 + lane;
        const float hv = hb_[k];
#pragma unroll
        for (int a = 0; a < Aa; a++) p[a] += Wa1[a * (2 * Hh) + k] * hv;
    }
#pragma unroll
    for (int a = 0; a < Aa; a++) {
        float v = p[a];
        v += __shfl_xor(v, 1, 64);
        v += __shfl_xor(v, 2, 64);
        v += __shfl_xor(v, 4, 64);
        v += __shfl_xor(v, 8, 64);
        v += __shfl_xor(v, 16, 64);
        v += __shfl_xor(v, 32, 64);
        if (lane == 0) part[w][a] = v;
    }
    __syncthreads();
    if (t < Aa)
        hpart[b * 16 + t] = part[0][t] + part[1][t] + part[2][t] + part[3][t];
}

// ---------------------------------------------------------------------------
// Fused scores + e: for 16 m-rows per wave, MFMA enc[m][:] @ Wa1_enc^T,
// then e[m] = sum_a Wa2[a]*tanh(acc + hpart[b][a]) reduced across the 16
// MFMA columns with shfl_xor. Writes e_t[b][s] (transposed for softmax).
// Eliminates the epre buffer + standalone softmax e-gather entirely.
// grid(512), block(256)
__global__ __launch_bounds__(256) void scores_e_kernel(
    const float* __restrict__ enc,
    const float* __restrict__ Wa1,
    const float* __restrict__ Wa2,
    const float* __restrict__ hpart,
    float* __restrict__ e_t) {   // [Bb][Ss]
    const int t = threadIdx.x;
    const int w = t >> 6, lane = t & 63;
    const int col = lane & 15, quad = lane >> 4;
    const int m0 = (blockIdx.x * 4 + w) * 16;
    const int bb = m0 & 63;            // b of row m0 (m0 multiple of 16)
    const bool valid = (col < Aa);
    const int wa_row = valid ? col : 0;

    const float* erow = enc + (size_t)(m0 + col) * Hh + quad * 8;
    const float* wrow = Wa1 + (size_t)wa_row * (2 * Hh) + Hh + quad * 8;

    f32x4 acc = {0.f, 0.f, 0.f, 0.f};
#pragma unroll 4
    for (int c = 0; c < 32; c++) {  // 32 chunks of 32 k (full K=1024, no split)
        float4 a0 = *(const float4*)(erow + c * 32);
        float4 a1 = *(const float4*)(erow + c * 32 + 4);
        bf16x8 af = cvt8(a0, a1);
        bf16x8 bf;
        if (valid) {
            float4 b0 = *(const float4*)(wrow + c * 32);
            float4 b1 = *(const float4*)(wrow + c * 32 + 4);
            bf = cvt8(b0, b1);
        } else {
            bf = (bf16x8){0, 0, 0, 0, 0, 0, 0, 0};
        }
        acc = __builtin_amdgcn_mfma_f32_16x16x32_bf16(af, bf, acc, 0, 0, 0);
    }

    // e-phase: v[r] = Wa2[col]*tanh(acc[r] + hpart[b_r][col]); reduce over col.
    const float w2 = valid ? Wa2[col] : 0.f;
    float v[4];
#pragma unroll
    for (int r = 0; r < 4; r++) {
        const int mr = quad * 4 + r;
        const float hp = valid ? hpart[(bb + mr) * 16 + col] : 0.f;
        v[r] = w2 * tanhf(acc[r] + hp);
    }
#pragma unroll
    for (int r = 0; r < 4; r++) {
        v[r] += __shfl_xor(v[r], 1, 16);
        v[r] += __shfl_xor(v[r], 2, 16);
        v[r] += __shfl_xor(v[r], 4, 16);
        v[r] += __shfl_xor(v[r], 8, 16);
    }
    if (col == 0) {
#pragma unroll
        for (int r = 0; r < 4; r++) {
            const int m = m0 + quad * 4 + r;
            e_t[(size_t)(m & 63) * Ss + (m >> 6)] = v[r];
        }
    }
}

// ---------------------------------------------------------------------------
// Fused softmax + context partials. Each block (b, sc) recomputes the
// softmax stats of e_t[b][:] (2 KB, L2-hot, shfl + 2 barriers), stages the
// 512 exp's in LDS, then accumulates its 32-s chunk of the context.
// cpart[sc][b][h] = sum_{s in chunk} alpha[s,b]*enc[s,b,h]
// grid(64,16), block(256)
__global__ __launch_bounds__(256) void context_kernel(const float* __restrict__ enc,
                                                      const float* __restrict__ e_t,
                                                      float* __restrict__ cpart) {
    __shared__ float al[Ss];
    __shared__ float sred[8];
    const int b = blockIdx.x, sc = blockIdx.y, t = threadIdx.x;
    const int w = t >> 6, lane = t & 63;

    const float x0 = e_t[(size_t)b * Ss + t];
    const float x1 = e_t[(size_t)b * Ss + 256 + t];
    float mx = fmaxf(x0, x1);
    mx = fmaxf(mx, __shfl_xor(mx, 1, 64));
    mx = fmaxf(mx, __shfl_xor(mx, 2, 64));
    mx = fmaxf(mx, __shfl_xor(mx, 4, 64));
    mx = fmaxf(mx, __shfl_xor(mx, 8, 64));
    mx = fmaxf(mx, __shfl_xor(mx, 16, 64));
    mx = fmaxf(mx, __shfl_xor(mx, 32, 64));
    if (lane == 0) sred[w] = mx;
    __syncthreads();
    const float MX = fmaxf(fmaxf(sred[0], sred[1]), fmaxf(sred[2], sred[3]));
    const float e0 = expf(x0 - MX), e1 = expf(x1 - MX);
    al[t] = e0;
    al[t + 256] = e1;
    float su = e0 + e1;
    su += __shfl_xor(su, 1, 64);
    su += __shfl_xor(su, 2, 64);
    su += __shfl_xor(su, 4, 64);
    su += __shfl_xor(su, 8, 64);
    su += __shfl_xor(su, 16, 64);
    su += __shfl_xor(su, 32, 64);
    if (lane == 0) sred[4 + w] = su;
    __syncthreads();
    const float inv = 1.f / (sred[4] + sred[5] + sred[6] + sred[7]);

    const float4* enc4 = (const float4*)enc;
    float4 acc = {0.f, 0.f, 0.f, 0.f};
    const int s0 = sc * 32;
#pragma unroll 4
    for (int i = 0; i < 32; ++i) {
        const int s = s0 + i;
        const float a = al[s] * inv;   // LDS broadcast
        float4 ev = enc4[(size_t)(s * Bb + b) * 256 + t];
        acc.x += a * ev.x;
        acc.y += a * ev.y;
        acc.z += a * ev.z;
        acc.w += a * ev.w;
    }
    ((float4*)cpart)[((size_t)sc * Bb + b) * 256 + t] = acc;
}

// ---------------------------------------------------------------------------
// xc: reduce 16 context partials, build bf16 A-operands:
// xcb[b] = bf16([emb[tok_b] | c[b]]), hb[b] = bf16(h[b])
// grid(64), block(256)
__global__ __launch_bounds__(256) void xc_kernel(const int* __restrict__ dec_input,
                                                 const float* __restrict__ emb,
                                                 const float* __restrict__ cpart,
                                                 const float* __restrict__ h,
                                                 short* __restrict__ xcb,
                                                 short* __restrict__ hb) {
    const int b = blockIdx.x, t = threadIdx.x;
    const int tok = dec_input[b];
    float4 cv = {0.f, 0.f, 0.f, 0.f};
#pragma unroll
    for (int p = 0; p < 16; p++) {
        float4 v = ((const float4*)cpart)[((size_t)p * Bb + b) * 256 + t];
        cv.x += v.x; cv.y += v.y; cv.z += v.z; cv.w += v.w;
    }
    float4 ev = ((const float4*)(emb + (size_t)tok * Ee))[t];
    float4 hv = ((const float4*)(h + (size_t)b * Hh))[t];
    s16x4 e4 = {f2bf(ev.x), f2bf(ev.y), f2bf(ev.z), f2bf(ev.w)};
    s16x4 c4 = {f2bf(cv.x), f2bf(cv.y), f2bf(cv.z), f2bf(cv.w)};
    s16x4 h4v = {f2bf(hv.x), f2bf(hv.y), f2bf(hv.z), f2bf(hv.w)};
    ((s16x4*)(xcb + (size_t)b * 2048))[t] = e4;
    ((s16x4*)(xcb + (size_t)b * 2048 + 1024))[t] = c4;
    ((s16x4*)(hb + (size_t)b * 1024))[t] = h4v;
}

// ---------------------------------------------------------------------------
// Streaming MFMA GEMM: C[p][64][N] = bf16(A)[64][Kp] @ bf16(W[N][Kp])^T (+bias)
// Templated on K / KLEN so trip counts are compile-time (load pipelining).
// Wave w owns 16 cols (n0=blk*64+w*16), 64 rows as 4 16x16 tiles.
// blockIdx.y = k-split p; partials written to C + p*64*N.
template<int K, int KLEN>
__global__ __launch_bounds__(256) void gemm_mfma_kernel(
    const short* __restrict__ Abf,  // [64][K] bf16
    const float* __restrict__ W,    // [N][K] fp32
    const float* __restrict__ bias, // or nullptr (only valid when ksplit==1)
    float* __restrict__ C,
    int N) {
    const int t = threadIdx.x;
    const int w = t >> 6, lane = t & 63;
    const int col = lane & 15, quad = lane >> 4;
    const int n0 = blockIdx.x * 64 + w * 16;
    const int kb0 = blockIdx.y * KLEN;

    f32x4 acc[4];
#pragma unroll
    for (int mt = 0; mt < 4; mt++) acc[mt] = (f32x4){0.f, 0.f, 0.f, 0.f};

    const float* wrow = W + (size_t)(n0 + col) * K + kb0 + quad * 8;
    const short* arow = Abf + (size_t)col * K + kb0 + quad * 8;

#pragma unroll 2
    for (int kb = 0; kb < KLEN; kb += 64) {
        float4 w0 = *(const float4*)(wrow + kb);
        float4 w1 = *(const float4*)(wrow + kb + 4);
        float4 w2 = *(const float4*)(wrow + kb + 32);
        float4 w3 = *(const float4*)(wrow + kb + 36);
        bf16x8 bf0 = cvt8(w0, w1);
        bf16x8 bf1 = cvt8(w2, w3);
        bf16x8 a0[4], a1[4];
#pragma unroll
        for (int mt = 0; mt < 4; mt++) {
            a0[mt] = *(const bf16x8*)(arow + (size_t)mt * 16 * K + kb);
            a1[mt] = *(const bf16x8*)(arow + (size_t)mt * 16 * K + kb + 32);
        }
#pragma unroll
        for (int mt = 0; mt < 4; mt++)
            acc[mt] = __builtin_amdgcn_mfma_f32_16x16x32_bf16(a0[mt], bf0, acc[mt], 0, 0, 0);
#pragma unroll
        for (int mt = 0; mt < 4; mt++)
            acc[mt] = __builtin_amdgcn_mfma_f32_16x16x32_bf16(a1[mt], bf1, acc[mt], 0, 0, 0);
    }

    const float bv = (bias != nullptr) ? bias[n0 + col] : 0.f;
    float* Cp = C + (size_t)blockIdx.y * 64 * N;
#pragma unroll
    for (int mt = 0; mt < 4; mt++) {
#pragma unroll
        for (int r = 0; r < 4; r++) {
            int m = mt * 16 + quad * 4 + r;
            Cp[(size_t)m * N + n0 + col] = acc[mt][r] + bv;
        }
    }
}

// ---------------------------------------------------------------------------
// GRU cell elementwise; sums gi (8) / gh (8) k-split partials, adds biases,
// emits fp32 h_new and bf16 h_new.
// grid(256), block(256)
__global__ __launch_bounds__(256) void gru_kernel(const float* __restrict__ gip,
                                                  const float* __restrict__ ghp,
                                                  const float* __restrict__ b_ih,
                                                  const float* __restrict__ b_hh,
                                                  const float* __restrict__ h,
                                                  float* __restrict__ h_new,
                                                  short* __restrict__ hnb) {
    const int idx = blockIdx.x * 256 + threadIdx.x;
    const int b = idx >> 10, j = idx & 1023;
    const size_t base = (size_t)b * (3 * Hh);
    float ir = b_ih[j], iz = b_ih[Hh + j], in_ = b_ih[2 * Hh + j];
    float hr = b_hh[j], hz = b_hh[Hh + j], hn = b_hh[2 * Hh + j];
#pragma unroll
    for (int p = 0; p < 8; p++) {
        const float* g = gip + (size_t)p * Bb * 3 * Hh + base;
        ir += g[j]; iz += g[Hh + j]; in_ += g[2 * Hh + j];
    }
#pragma unroll
    for (int p = 0; p < 8; p++) {
        const float* g = ghp + (size_t)p * Bb * 3 * Hh + base;
        hr += g[j]; hz += g[Hh + j]; hn += g[2 * Hh + j];
    }
    float r = 1.f / (1.f + expf(-(ir + hr)));
    float z = 1.f / (1.f + expf(-(iz + hz)));
    float n = tanhf(in_ + r * hn);
    float val = (1.f - z) * n + z * h[idx];
    h_new[idx] = val;
    hnb[idx] = f2bf(val);
}

// ---------------------------------------------------------------------------
extern "C" void kernel_launch(void* const* d_in, const int* in_sizes, int n_in,
                              void* d_out, int out_size, void* d_ws, size_t ws_size,
                              hipStream_t stream) {
    const int* dec_input = (const int*)d_in[0];
    const float* dec_hidden = (const float*)d_in[1];
    const float* enc = (const float*)d_in[2];
    const float* emb = (const float*)d_in[3];
    const float* Wa1 = (const float*)d_in[4];
    const float* Wa2 = (const float*)d_in[5];
    const float* W_ih = (const float*)d_in[6];
    const float* W_hh = (const float*)d_in[7];
    const float* b_ih = (const float*)d_in[8];
    const float* b_hh = (const float*)d_in[9];
    const float* W_out = (const float*)d_in[10];
    const float* b_out = (const float*)d_in[11];

    float* out = (float*)d_out;
    float* logits = out;                  // (B,V)
    float* h_new = out + (size_t)Bb * Vv; // (1,B,H)

    // Workspace layout (floats), lifetime-aliased:
    //   hpart     [0, 1024)
    //   e_t       [1024, 33792)           (64 x 512, transposed e)
    //   xcb(bf16) [33792, 99328)   = 131072 shorts
    //   hb (bf16) [99328, 132096)  = 65536 shorts
    //   hnb(bf16) [132096, 164864) = 65536 shorts
    //   region1   [164864, +1572864): cpart (16*65536=1048576) then gip (8*196608)
    //   region2   [1737728, +1572864): ghp (8*196608)
    float* ws = (float*)d_ws;
    float* hpart_ptr = ws;
    float* e_ptr = ws + 1024;
    short* xcb_ptr = (short*)(ws + 33792);
    short* hb_ptr = (short*)(ws + 99328);
    short* hnb_ptr = (short*)(ws + 132096);
    float* region1 = ws + 164864;
    float* region2 = ws + 1737728;
    float* cpart_ptr = region1;  // dead after xc
    float* gip_ptr = region1;    // written after xc
    float* ghp_ptr = region2;

    hpart_kernel<<<Bb, 256, 0, stream>>>(Wa1, dec_hidden, hpart_ptr);
    scores_e_kernel<<<Mm / 64, 256, 0, stream>>>(enc, Wa1, Wa2, hpart_ptr, e_ptr);
    context_kernel<<<dim3(Bb, 16), 256, 0, stream>>>(enc, e_ptr, cpart_ptr);
    xc_kernel<<<Bb, 256, 0, stream>>>(dec_input, emb, cpart_ptr, dec_hidden,
                                      xcb_ptr, hb_ptr);

    // gi = xc @ W_ih^T : N=3072, K=2048, k-split 8 (Klen=256)
    gemm_mfma_kernel<2048, 256><<<dim3(3 * Hh / 64, 8), 256, 0, stream>>>(
        xcb_ptr, W_ih, nullptr, gip_ptr, 3 * Hh);
    // gh = h @ W_hh^T : N=3072, K=1024, k-split 8 (Klen=128)
    gemm_mfma_kernel<1024, 128><<<dim3(3 * Hh / 64, 8), 256, 0, stream>>>(
        hb_ptr, W_hh, nullptr, ghp_ptr, 3 * Hh);

    gru_kernel<<<(Bb * Hh) / 256, 256, 0, stream>>>(gip_ptr, ghp_ptr, b_ih, b_hh,
                                                    dec_hidden, h_new, hnb_ptr);

    // logits = h_new @ W_out^T + b_out : N=32000, K=1024, no split
    gemm_mfma_kernel<1024, 1024><<<dim3(Vv / 64, 1), 256, 0, stream>>>(
        hnb_ptr, W_out, b_out, logits, Vv);
}